// Round 8
// baseline (798.482 us; speedup 1.0000x reference)
//
#include <hip/hip_runtime.h>

typedef __attribute__((ext_vector_type(8))) short short8;
typedef __attribute__((ext_vector_type(4))) float f32x4;

// ZERO d_ws usage. Scratch map:
//   d_out f32 16MB: [0,8M) G0 bf16 -> XN bf16 -> OUT(b<16) f32
//                   [8M,16M) X1 bf16 -> X2 bf16 (same-index RMW) -> OUT(b>=16) f32
//   x (d_in[0], 16MB, dead after GRU L1): CW bf16 [0,655K) -> K bf16 [0,8M), V bf16 [8M,16M)
//                   then X2HI bf16 [0,4M) (over dead K(b<16)) for attn launch B
//   b_hh (d_in[4], 6KB, dead after GRU scans): BN stats (512 f32)

__device__ __forceinline__ unsigned short f2bf(float f) {
  union { float f; unsigned u; } c; c.f = f;
  return (unsigned short)((c.u + 0x7fffu + ((c.u >> 16) & 1u)) >> 16);
}
__device__ __forceinline__ float bf2f(unsigned short u) {
  union { unsigned u; float f; } c; c.u = ((unsigned)u) << 16; return c.f;
}
__device__ __forceinline__ short8 cvt8(const float* __restrict__ p) {
  float4 a = *(const float4*)p, b = *(const float4*)(p + 4);
  short8 r;
  r[0] = (short)f2bf(a.x); r[1] = (short)f2bf(a.y); r[2] = (short)f2bf(a.z); r[3] = (short)f2bf(a.w);
  r[4] = (short)f2bf(b.x); r[5] = (short)f2bf(b.y); r[6] = (short)f2bf(b.z); r[7] = (short)f2bf(b.w);
  return r;
}

__global__ void zero_stats(float* __restrict__ s) { s[threadIdx.x] = 0.f; }

// conv_w (fo,fi,5,1) f32 -> [k][fo*256+fi] bf16 (into dead x buffer)
__global__ void permute_cw(const float* __restrict__ w, unsigned short* __restrict__ out) {
  int i = blockIdx.x * 256 + threadIdx.x;   // fo*256+fi, 65536 total
  float v0 = w[(long)i*5+0], v1 = w[(long)i*5+1], v2 = w[(long)i*5+2];
  float v3 = w[(long)i*5+3], v4 = w[(long)i*5+4];
  out[0*65536+i]=f2bf(v0); out[1*65536+i]=f2bf(v1); out[2*65536+i]=f2bf(v2);
  out[3*65536+i]=f2bf(v3); out[4*65536+i]=f2bf(v4);
}

// ---------------- fused GRU: per-(chunk,dir) WG does gate-GEMM (MFMA) + 64-step scan ----------------
// 768 threads = 12 waves. Scan weights split 2 threads/gate-row (64 VGPRs each -> NO SPILL;
// round-7 counters showed wv[32]=128 VGPRs spilled at VGPR_Count=84, scratch reload = 87% of kernel time).
__global__ __launch_bounds__(768) void fused_gru(
    const float* __restrict__ xf,           // layer0: x input; layer1: residual x
    const unsigned short* __restrict__ g0,  // layer1: G0 bf16 (unused layer0)
    const float* __restrict__ w_ih, const float* __restrict__ w_hh,
    const float* __restrict__ b_ih, const float* __restrict__ b_hh,
    unsigned short* __restrict__ outb, int layer)
{
  __shared__ unsigned short gs[64][392];   // gate preacts bf16 (+bias), padded stride
  __shared__ float hbuf[2][128];
  __shared__ float ghs[384];
  int c = blockIdx.x, d = blockIdx.y;
  int t = threadIdx.x;
  int wid = t >> 6, lr = t & 15, lk = (t & 63) >> 4;
  long wb = (long)((layer*2 + d) * 384);

  // GEMM: gates[64t][384g] = X_chunk(64x256) @ W_ih_dir^T; wave w owns cols [w*32, w*32+32)
  f32x4 acc[4][2] = {};
  for (int k0 = 0; k0 < 256; k0 += 32) {
    short8 af[4], bf[2];
#pragma unroll
    for (int mt = 0; mt < 4; ++mt) {
      long row = (long)c*64 + mt*16 + lr;
      if (layer == 0) af[mt] = cvt8(&xf[row*256 + k0 + lk*8]);
      else            af[mt] = *(const short8*)&g0[row*256 + k0 + lk*8];
    }
#pragma unroll
    for (int nt = 0; nt < 2; ++nt) {
      int g = wid*32 + nt*16 + lr;
      bf[nt] = cvt8(&w_ih[(wb + g)*256 + k0 + lk*8]);
    }
#pragma unroll
    for (int mt = 0; mt < 4; ++mt)
#pragma unroll
      for (int nt = 0; nt < 2; ++nt)
        acc[mt][nt] = __builtin_amdgcn_mfma_f32_16x16x32_bf16(af[mt], bf[nt], acc[mt][nt], 0, 0, 0);
  }
#pragma unroll
  for (int nt = 0; nt < 2; ++nt) {
    int g = wid*32 + nt*16 + lr;
    float bi = b_ih[wb + g];
#pragma unroll
    for (int mt = 0; mt < 4; ++mt)
#pragma unroll
      for (int r = 0; r < 4; ++r)
        gs[mt*16 + lk*4 + r][g] = f2bf(acc[mt][nt][r] + bi);
  }

  // scan: thread pair (2j, 2j+1) covers gate j; each holds 64 of the 128 w_hh weights
  int j = t >> 1, half = t & 1;
  const float* wrow = &w_hh[(wb + j)*128 + half*64];
  float4 wv[16];
#pragma unroll
  for (int i = 0; i < 16; ++i) wv[i] = ((const float4*)wrow)[i];
  float bh = b_hh[wb + j];
  if (t < 128) hbuf[0][t] = 0.f;
  __syncthreads();
  int cur = 0;
  for (int tt = 0; tt < 64; ++tt) {
    int te = d ? (63 - tt) : tt;
    const float4* h4 = (const float4*)hbuf[cur] + half*16;
    float a0 = 0.f, a1 = 0.f, a2 = 0.f, a3 = 0.f;
#pragma unroll
    for (int i = 0; i < 16; ++i) {
      float4 hh = h4[i];
      a0 += wv[i].x*hh.x; a1 += wv[i].y*hh.y; a2 += wv[i].z*hh.z; a3 += wv[i].w*hh.w;
    }
    float s = (a0 + a1) + (a2 + a3);
    s += __shfl_xor(s, 1);
    if (half == 0) ghs[j] = s + bh;
    __syncthreads();
    if (t < 128) {
      float xr = bf2f(gs[te][t]), xz = bf2f(gs[te][t+128]), xn = bf2f(gs[te][t+256]);
      float gr = ghs[t], gz = ghs[t+128], gn = ghs[t+256];
      float r = 1.f/(1.f + __expf(-(xr + gr)));
      float z = 1.f/(1.f + __expf(-(xz + gz)));
      float na = xn + r*gn;
      na = fminf(fmaxf(na, -30.f), 30.f);
      float e2 = __expf(-2.f*na);
      float n = (1.f - e2)/(1.f + e2);
      float hn = (1.f - z)*n + z*hbuf[cur][t];
      hbuf[cur^1][t] = hn;
      long oi = ((long)c*64 + te)*256 + d*128 + t;
      if (layer == 0) outb[oi] = f2bf(hn);
      else            outb[oi] = f2bf(xf[oi] + hn);
    }
    __syncthreads();
    cur ^= 1;
  }
}

// ---------------- BatchNorm (X1 bf16) ----------------
__global__ __launch_bounds__(256) void bn_stats(const unsigned short* __restrict__ x1, float* __restrict__ stats) {
  int f = threadIdx.x;
  long r0 = (long)blockIdx.x * 64;
  float s = 0.f, s2 = 0.f;
  for (int r = 0; r < 64; ++r) {
    float v = bf2f(x1[(r0 + r)*256 + f]);
    s += v; s2 += v*v;
  }
  atomicAdd(&stats[f], s);
  atomicAdd(&stats[256 + f], s2);
}

__global__ __launch_bounds__(256) void bn_apply(
    const unsigned short* __restrict__ x1, const float* __restrict__ stats,
    const float* __restrict__ gamma, const float* __restrict__ beta,
    unsigned short* __restrict__ xn_bf)
{
  int i = blockIdx.x * 256 + threadIdx.x;
  int f = i & 255;
  float mean = stats[f] * (1.f/16384.f);
  float var  = stats[256 + f] * (1.f/16384.f) - mean*mean;
  float inv  = rsqrtf(var + 1e-5f);
  xn_bf[i] = f2bf((bf2f(x1[i]) - mean) * inv * gamma[f] + beta[f]);
}

// ---------------- conv as 5 shifted GEMMs (LDS-free); x2 = x1 + leaky(conv+b), same-index RMW ----------------
__global__ __launch_bounds__(256) void conv_gemm(
    const unsigned short* __restrict__ xn, const unsigned short* __restrict__ cw,
    const float* __restrict__ cb, unsigned short* io)
{
  int m0 = blockIdx.x*64, n0 = blockIdx.y*64;
  int t = threadIdx.x, w = t >> 6, lr = t & 15, lk = (t & 63) >> 4;
  f32x4 acc[4] = {};
  int mrow = m0 + w*16 + lr;
  int sloc = mrow & 511;
  for (int kk = 0; kk < 5; ++kk) {
    int sh = sloc + kk - 2;
    bool ok = (sh >= 0) && (sh < 512);
    long arow = (long)mrow + kk - 2;
    for (int kb = 0; kb < 256; kb += 32) {
      short8 af = {};
      if (ok) af = *(const short8*)&xn[arow*256 + kb + lk*8];
#pragma unroll
      for (int g = 0; g < 4; ++g) {
        short8 bf = *(const short8*)&cw[(long)kk*65536 + (long)(n0 + g*16 + lr)*256 + kb + lk*8];
        acc[g] = __builtin_amdgcn_mfma_f32_16x16x32_bf16(af, bf, acc[g], 0, 0, 0);
      }
    }
  }
#pragma unroll
  for (int g = 0; g < 4; ++g) {
    int fo = n0 + g*16 + lr;
    float bv = cb[fo];
#pragma unroll
    for (int r = 0; r < 4; ++r) {
      long row = m0 + w*16 + lk*4 + r;
      float cv = acc[g][r] + bv;
      cv = fmaxf(cv, 0.1f*cv);
      long idx = row*256 + fo;
      io[idx] = f2bf(bf2f(io[idx]) + cv);
    }
  }
}

// ---------------- K/V projection (LDS-free GEMM, B from f32 weights inline) ----------------
__global__ __launch_bounds__(256) void kv_proj(
    const unsigned short* __restrict__ A, const float* __restrict__ wk,
    const float* __restrict__ wvv,
    unsigned short* __restrict__ kb, unsigned short* __restrict__ vb)
{
  int m0 = blockIdx.x*64, n0 = blockIdx.y*64;
  int t = threadIdx.x, w = t >> 6, lr = t & 15, lk = (t & 63) >> 4;
  f32x4 acc[4] = {};
  long arow = (long)(m0 + w*16 + lr);
  for (int k0 = 0; k0 < 256; k0 += 32) {
    short8 af = *(const short8*)&A[arow*256 + k0 + lk*8];
#pragma unroll
    for (int g = 0; g < 4; ++g) {
      int col = n0 + g*16 + lr;
      const float* ws = (col < 256) ? wk : wvv;
      short8 bf = cvt8(&ws[(long)(col & 255)*256 + k0 + lk*8]);
      acc[g] = __builtin_amdgcn_mfma_f32_16x16x32_bf16(af, bf, acc[g], 0, 0, 0);
    }
  }
#pragma unroll
  for (int g = 0; g < 4; ++g) {
    int col = n0 + g*16 + lr;
    int which = col >> 8, hh = (col >> 5) & 7, dd = col & 31;
    unsigned short* dst = (which == 0) ? kb : vb;
#pragma unroll
    for (int r = 0; r < 4; ++r) {
      int row = m0 + w*16 + lk*4 + r;
      int b = row >> 9, s = row & 511;
      dst[((long)(b*8 + hh)*512 + s)*32 + dd] = f2bf(acc[g][r]);
    }
  }
}

// ---------------- fused attention: Q-gen + QK^T + relbias + softmax + PV + leaky + LN + residual ----------------
__global__ __launch_bounds__(256) void attn(
    const unsigned short* __restrict__ kbuf, const unsigned short* __restrict__ vbuf,
    const unsigned short* __restrict__ x2, const float* __restrict__ wq,
    const float* __restrict__ rel, const float* __restrict__ lng, const float* __restrict__ lnb,
    float* __restrict__ outf, int b_base, int x2_boff)
{
  __shared__ __align__(16) unsigned short Qs[64*32];
  __shared__ __align__(16) unsigned short Ks[64*32];
  __shared__ __align__(16) unsigned short Vt[32*64];
  __shared__ __align__(16) unsigned short Ps[4][16*64];
  __shared__ float bl[128];
  int s0 = blockIdx.x*64, h = blockIdx.y, bg = b_base + blockIdx.z;
  int t = threadIdx.x;
  int w = t >> 6, l = t & 63, lr = l & 15, lk = l >> 4;
  int st = t >> 2, sc = (t & 3)*8;
  long bh = (long)(bg*8 + h);
  long x2r0 = (long)(bg - x2_boff)*512;

  // Q-gen: 64x32 tile from X2 rows, wq f32 inline-converted; scaled by 1/sqrt(D)
  {
    f32x4 qa[2] = {};
    long arow = x2r0 + s0 + w*16 + lr;
    for (int k0 = 0; k0 < 256; k0 += 32) {
      short8 af = *(const short8*)&x2[arow*256 + k0 + lk*8];
#pragma unroll
      for (int nt = 0; nt < 2; ++nt) {
        short8 bf = cvt8(&wq[((long)h*32 + nt*16 + lr)*256 + k0 + lk*8]);
        qa[nt] = __builtin_amdgcn_mfma_f32_16x16x32_bf16(af, bf, qa[nt], 0, 0, 0);
      }
    }
#pragma unroll
    for (int nt = 0; nt < 2; ++nt)
#pragma unroll
      for (int r = 0; r < 4; ++r)
        Qs[(w*16 + lk*4 + r)*32 + nt*16 + lr] = f2bf(qa[nt][r] * 0.17677669529663687f);
  }
  __syncthreads();
  short8 qf = *(const short8*)&Qs[(w*16 + lr)*32 + lk*8];

  f32x4 o[2] = {};
  float mrun[4] = {-3e38f, -3e38f, -3e38f, -3e38f};
  float lrun[4] = {0.f, 0.f, 0.f, 0.f};

  for (int t0 = 0; t0 < 512; t0 += 64) {
    __syncthreads();
    *(short8*)&Ks[st*32 + sc] = *(const short8*)&kbuf[(bh*512 + t0 + st)*32 + sc];
    short8 vv = *(const short8*)&vbuf[(bh*512 + t0 + st)*32 + sc];
#pragma unroll
    for (int jj = 0; jj < 8; ++jj) Vt[(sc + jj)*64 + st] = (unsigned short)vv[jj];
    if (t < 127) {
      int dd = s0 - t0 + t - 63;
      bl[t] = rel[(long)h*512 + (dd < 0 ? -dd : dd)];
    }
    __syncthreads();

    f32x4 zz = {};
    f32x4 sacc[4];
#pragma unroll
    for (int g = 0; g < 4; ++g) {
      short8 bf = *(const short8*)&Ks[(g*16 + lr)*32 + lk*8];
      sacc[g] = __builtin_amdgcn_mfma_f32_16x16x32_bf16(qf, bf, zz, 0, 0, 0);
    }
    float mx[4] = {-3e38f, -3e38f, -3e38f, -3e38f};
#pragma unroll
    for (int g = 0; g < 4; ++g)
#pragma unroll
      for (int r = 0; r < 4; ++r) {
        int iq = w*16 + lk*4 + r, jt = g*16 + lr;
        float val = sacc[g][r] + bl[iq - jt + 63];
        sacc[g][r] = val;
        mx[r] = fmaxf(mx[r], val);
      }
#pragma unroll
    for (int off = 1; off < 16; off <<= 1)
#pragma unroll
      for (int r = 0; r < 4; ++r) mx[r] = fmaxf(mx[r], __shfl_xor(mx[r], off));
    float scl[4];
#pragma unroll
    for (int r = 0; r < 4; ++r) {
      float mn = fmaxf(mrun[r], mx[r]);
      scl[r] = __expf(mrun[r] - mn);
      mrun[r] = mn;
    }
    float rs[4] = {0.f, 0.f, 0.f, 0.f};
#pragma unroll
    for (int g = 0; g < 4; ++g)
#pragma unroll
      for (int r = 0; r < 4; ++r) {
        float p = __expf(sacc[g][r] - mrun[r]);
        sacc[g][r] = p;
        rs[r] += p;
      }
#pragma unroll
    for (int off = 1; off < 16; off <<= 1)
#pragma unroll
      for (int r = 0; r < 4; ++r) rs[r] += __shfl_xor(rs[r], off);
#pragma unroll
    for (int r = 0; r < 4; ++r) {
      lrun[r] = lrun[r]*scl[r] + rs[r];
      o[0][r] *= scl[r];
      o[1][r] *= scl[r];
    }
#pragma unroll
    for (int g = 0; g < 4; ++g)
#pragma unroll
      for (int r = 0; r < 4; ++r)
        Ps[w][(lk*4 + r)*64 + g*16 + lr] = f2bf(sacc[g][r]);
    // Ps[w] is wave-private; same-wave DS write->read is in-order
#pragma unroll
    for (int ks = 0; ks < 2; ++ks) {
      short8 pa = *(const short8*)&Ps[w][lr*64 + ks*32 + lk*8];
#pragma unroll
      for (int g2 = 0; g2 < 2; ++g2) {
        short8 bv = *(const short8*)&Vt[(g2*16 + lr)*64 + ks*32 + lk*8];
        o[g2] = __builtin_amdgcn_mfma_f32_16x16x32_bf16(pa, bv, o[g2], 0, 0, 0);
      }
    }
  }

  float lg0 = lng[h*32 + lr], lg1 = lng[h*32 + 16 + lr];
  float lb0 = lnb[h*32 + lr], lb1 = lnb[h*32 + 16 + lr];
#pragma unroll
  for (int r = 0; r < 4; ++r) {
    float invl = 1.f / lrun[r];
    float a0 = o[0][r]*invl; a0 = fmaxf(a0, 0.1f*a0);
    float a1 = o[1][r]*invl; a1 = fmaxf(a1, 0.1f*a1);
    float s1 = a0 + a1, s2 = a0*a0 + a1*a1;
#pragma unroll
    for (int off = 1; off < 16; off <<= 1) {
      s1 += __shfl_xor(s1, off);
      s2 += __shfl_xor(s2, off);
    }
    float mu = s1*(1.f/32.f);
    float var = s2*(1.f/32.f) - mu*mu;
    float inv = rsqrtf(var + 1e-5f);
    int row = s0 + w*16 + lk*4 + r;
    long x2i = (x2r0 + row)*256 + h*32;
    long obase = ((long)(bg*512 + row))*256 + h*32;
    outf[obase + lr]      = bf2f(x2[x2i + lr])      + (a0 - mu)*inv*lg0 + lb0;
    outf[obase + 16 + lr] = bf2f(x2[x2i + 16 + lr]) + (a1 - mu)*inv*lg1 + lb1;
  }
}

// ---------------- host launch ----------------
extern "C" void kernel_launch(void* const* d_in, const int* in_sizes, int n_in,
                              void* d_out, int out_size, void* d_ws, size_t ws_size,
                              hipStream_t stream) {
  const float* x      = (const float*)d_in[0];
  const float* w_ih   = (const float*)d_in[1];
  const float* w_hh   = (const float*)d_in[2];
  const float* b_ih   = (const float*)d_in[3];
  const float* b_hh   = (const float*)d_in[4];
  const float* bn_g   = (const float*)d_in[5];
  const float* bn_b   = (const float*)d_in[6];
  const float* conv_w = (const float*)d_in[7];
  const float* conv_b = (const float*)d_in[8];
  const float* wq     = (const float*)d_in[9];
  const float* wk     = (const float*)d_in[10];
  const float* wvv    = (const float*)d_in[11];
  const float* rel    = (const float*)d_in[12];
  const float* ln_g   = (const float*)d_in[13];
  const float* ln_b   = (const float*)d_in[14];

  float* outf = (float*)d_out;
  unsigned short* dob = (unsigned short*)d_out;
  unsigned short* G0  = dob;              // [0,8M) bytes
  unsigned short* X1  = dob + 4194304;    // [8M,16M) bytes; becomes X2 in place
  unsigned short* XN  = dob;              // [0,8M) after G0 dead

  unsigned short* xs  = (unsigned short*)d_in[0];  // dead-input scratch (x)
  unsigned short* CW  = xs;                        // [0,655360) bytes in x
  unsigned short* KB  = xs;                        // [0,8M) in x
  unsigned short* VB  = xs + 4194304;              // [8M,16M) in x
  unsigned short* X2HI= xs;                        // [0,4M) in x (over dead K(b<16))
  float* STATS = (float*)d_in[4];                  // dead b_hh (6KB >= 2KB)

  // GRU layer 0 -> G0 bf16; layer 1 (+residual x) -> X1 bf16
  fused_gru<<<dim3(256, 2), 768, 0, stream>>>(x, nullptr, w_ih, w_hh, b_ih, b_hh, G0, 0);
  fused_gru<<<dim3(256, 2), 768, 0, stream>>>(x, G0,      w_ih, w_hh, b_ih, b_hh, X1, 1);

  // x and b_hh now dead -> scratch
  permute_cw<<<256, 256, 0, stream>>>(conv_w, CW);
  zero_stats<<<1, 512, 0, stream>>>(STATS);

  // BatchNorm
  bn_stats<<<256, 256, 0, stream>>>(X1, STATS);
  bn_apply<<<16384, 256, 0, stream>>>(X1, STATS, bn_g, bn_b, XN);

  // Conv + leaky + residual: X1 -> X2 (same-index RMW in d_out upper half)
  conv_gemm<<<dim3(256, 4), 256, 0, stream>>>(XN, CW, conv_b, X1);

  // K/V projection into dead x
  kv_proj<<<dim3(256, 8), 256, 0, stream>>>(X1, wk, wvv, KB, VB);

  // attention launch A: b<16, OUT f32 -> d_out[0,8M)
  attn<<<dim3(8, 8, 16), 256, 0, stream>>>(KB, VB, X1, wq, rel, ln_g, ln_b, outf, 0, 0);

  // move X2(b>=16) (4MB) out of d_out before launch B overwrites it
  hipMemcpyAsync(X2HI, (char*)d_out + 12582912, 4194304, hipMemcpyDeviceToDevice, stream);

  // attention launch B: b>=16, X2 from copy in x, OUT f32 -> d_out[8M,16M)
  attn<<<dim3(8, 8, 16), 256, 0, stream>>>(KB, VB, X2HI, wq, rel, ln_g, ln_b, outf, 16, 16);
}

// Round 10
// 708.356 us; speedup vs baseline: 1.1272x; 1.1272x over previous
//
#include <hip/hip_runtime.h>

typedef __attribute__((ext_vector_type(8))) short short8;
typedef __attribute__((ext_vector_type(4))) float f32x4;

// ZERO d_ws usage. Scratch map:
//   d_out f32 16MB: [0,8M) G0 bf16 -> XN bf16 -> OUT(b<16) f32
//                   [8M,16M) X1 bf16 -> X2 bf16 (same-index RMW) -> OUT(b>=16) f32
//   x (d_in[0], 16MB, dead after GRU L1): CW bf16 [0,655K) -> K bf16 [0,8M), V bf16 [8M,16M)
//                   then X2HI bf16 [0,4M) (over dead K(b<16)) for attn launch B
//   b_hh (d_in[4], 6KB, dead after GRU scans): BN stats (512 f32)

__device__ __forceinline__ unsigned short f2bf(float f) {
  union { float f; unsigned u; } c; c.f = f;
  return (unsigned short)((c.u + 0x7fffu + ((c.u >> 16) & 1u)) >> 16);
}
__device__ __forceinline__ float bf2f(unsigned short u) {
  union { unsigned u; float f; } c; c.u = ((unsigned)u) << 16; return c.f;
}
__device__ __forceinline__ short8 cvt8(const float* __restrict__ p) {
  float4 a = *(const float4*)p, b = *(const float4*)(p + 4);
  short8 r;
  r[0] = (short)f2bf(a.x); r[1] = (short)f2bf(a.y); r[2] = (short)f2bf(a.z); r[3] = (short)f2bf(a.w);
  r[4] = (short)f2bf(b.x); r[5] = (short)f2bf(b.y); r[6] = (short)f2bf(b.z); r[7] = (short)f2bf(b.w);
  return r;
}

__global__ void zero_stats(float* __restrict__ s) { s[threadIdx.x] = 0.f; }

// conv_w (fo,fi,5,1) f32 -> [k][fo*256+fi] bf16 (into dead x buffer)
__global__ void permute_cw(const float* __restrict__ w, unsigned short* __restrict__ out) {
  int i = blockIdx.x * 256 + threadIdx.x;   // fo*256+fi, 65536 total
  float v0 = w[(long)i*5+0], v1 = w[(long)i*5+1], v2 = w[(long)i*5+2];
  float v3 = w[(long)i*5+3], v4 = w[(long)i*5+4];
  out[0*65536+i]=f2bf(v0); out[1*65536+i]=f2bf(v1); out[2*65536+i]=f2bf(v2);
  out[3*65536+i]=f2bf(v3); out[4*65536+i]=f2bf(v4);
}

// ---------------- fused GRU: per-(chunk,dir) WG does gate-GEMM (MFMA) + 64-step scan ----------------
// 768 threads = 12 waves. Scan weights split 2 threads/gate-row, INTERLEAVED float4s
// (half h owns w[2i+h]; banks disjoint -> no LDS conflicts on h reads).
// __launch_bounds__(768,4) caps VGPR at 128 so the 64-reg weight array STAYS IN REGISTERS:
// r7 (VGPR=84) and r8 (VGPR=52) both spilled it; 6.4GB/dispatch scratch reload @ ~28.5TB/s
// == the measured 225us (L2-bound). This line is the whole fix.
__global__ __launch_bounds__(768, 4) void fused_gru(
    const float* __restrict__ xf,           // layer0: x input; layer1: residual x
    const unsigned short* __restrict__ g0,  // layer1: G0 bf16 (unused layer0)
    const float* __restrict__ w_ih, const float* __restrict__ w_hh,
    const float* __restrict__ b_ih, const float* __restrict__ b_hh,
    unsigned short* __restrict__ outb, int layer)
{
  __shared__ unsigned short gs[64][392];   // gate preacts bf16 (+bias), padded stride
  __shared__ float hbuf[2][128];
  __shared__ float ghs[384];
  int c = blockIdx.x, d = blockIdx.y;
  int t = threadIdx.x;
  int wid = t >> 6, lr = t & 15, lk = (t & 63) >> 4;
  long wb = (long)((layer*2 + d) * 384);

  // GEMM: gates[64t][384g] = X_chunk(64x256) @ W_ih_dir^T; wave w owns cols [w*32, w*32+32)
  f32x4 acc[4][2] = {};
  for (int k0 = 0; k0 < 256; k0 += 32) {
    short8 af[4], bf[2];
#pragma unroll
    for (int mt = 0; mt < 4; ++mt) {
      long row = (long)c*64 + mt*16 + lr;
      if (layer == 0) af[mt] = cvt8(&xf[row*256 + k0 + lk*8]);
      else            af[mt] = *(const short8*)&g0[row*256 + k0 + lk*8];
    }
#pragma unroll
    for (int nt = 0; nt < 2; ++nt) {
      int g = wid*32 + nt*16 + lr;
      bf[nt] = cvt8(&w_ih[(wb + g)*256 + k0 + lk*8]);
    }
#pragma unroll
    for (int mt = 0; mt < 4; ++mt)
#pragma unroll
      for (int nt = 0; nt < 2; ++nt)
        acc[mt][nt] = __builtin_amdgcn_mfma_f32_16x16x32_bf16(af[mt], bf[nt], acc[mt][nt], 0, 0, 0);
  }
#pragma unroll
  for (int nt = 0; nt < 2; ++nt) {
    int g = wid*32 + nt*16 + lr;
    float bi = b_ih[wb + g];
#pragma unroll
    for (int mt = 0; mt < 4; ++mt)
#pragma unroll
      for (int r = 0; r < 4; ++r)
        gs[mt*16 + lk*4 + r][g] = f2bf(acc[mt][nt][r] + bi);
  }

  // scan: thread pair (2j, 2j+1) covers gate j; half h holds interleaved float4s w[2i+h]
  int j = t >> 1, half = t & 1;
  const float4* wrow4 = (const float4*)&w_hh[(wb + j)*128];
  float4 wv[16];
#pragma unroll
  for (int i = 0; i < 16; ++i) wv[i] = wrow4[2*i + half];
  float bh = b_hh[wb + j];
  if (t < 128) hbuf[0][t] = 0.f;
  __syncthreads();
  int cur = 0;
  for (int tt = 0; tt < 64; ++tt) {
    int te = d ? (63 - tt) : tt;
    const float4* h4 = (const float4*)hbuf[cur];
    float a0 = 0.f, a1 = 0.f, a2 = 0.f, a3 = 0.f;
#pragma unroll
    for (int i = 0; i < 16; ++i) {
      float4 hh = h4[2*i + half];
      a0 += wv[i].x*hh.x; a1 += wv[i].y*hh.y; a2 += wv[i].z*hh.z; a3 += wv[i].w*hh.w;
    }
    float s = (a0 + a1) + (a2 + a3);
    s += __shfl_xor(s, 1);
    if (half == 0) ghs[j] = s + bh;
    __syncthreads();
    if (t < 128) {
      float xr = bf2f(gs[te][t]), xz = bf2f(gs[te][t+128]), xn = bf2f(gs[te][t+256]);
      float gr = ghs[t], gz = ghs[t+128], gn = ghs[t+256];
      float r = 1.f/(1.f + __expf(-(xr + gr)));
      float z = 1.f/(1.f + __expf(-(xz + gz)));
      float na = xn + r*gn;
      na = fminf(fmaxf(na, -30.f), 30.f);
      float e2 = __expf(-2.f*na);
      float n = (1.f - e2)/(1.f + e2);
      float hn = (1.f - z)*n + z*hbuf[cur][t];
      hbuf[cur^1][t] = hn;
      long oi = ((long)c*64 + te)*256 + d*128 + t;
      if (layer == 0) outb[oi] = f2bf(hn);
      else            outb[oi] = f2bf(xf[oi] + hn);
    }
    __syncthreads();
    cur ^= 1;
  }
}

// ---------------- BatchNorm (X1 bf16) ----------------
__global__ __launch_bounds__(256) void bn_stats(const unsigned short* __restrict__ x1, float* __restrict__ stats) {
  int f = threadIdx.x;
  long r0 = (long)blockIdx.x * 64;
  float s = 0.f, s2 = 0.f;
  for (int r = 0; r < 64; ++r) {
    float v = bf2f(x1[(r0 + r)*256 + f]);
    s += v; s2 += v*v;
  }
  atomicAdd(&stats[f], s);
  atomicAdd(&stats[256 + f], s2);
}

__global__ __launch_bounds__(256) void bn_apply(
    const unsigned short* __restrict__ x1, const float* __restrict__ stats,
    const float* __restrict__ gamma, const float* __restrict__ beta,
    unsigned short* __restrict__ xn_bf)
{
  int i = blockIdx.x * 256 + threadIdx.x;
  int f = i & 255;
  float mean = stats[f] * (1.f/16384.f);
  float var  = stats[256 + f] * (1.f/16384.f) - mean*mean;
  float inv  = rsqrtf(var + 1e-5f);
  xn_bf[i] = f2bf((bf2f(x1[i]) - mean) * inv * gamma[f] + beta[f]);
}

// ---------------- conv as 5 shifted GEMMs (LDS-free); x2 = x1 + leaky(conv+b), same-index RMW ----------------
__global__ __launch_bounds__(256) void conv_gemm(
    const unsigned short* __restrict__ xn, const unsigned short* __restrict__ cw,
    const float* __restrict__ cb, unsigned short* io)
{
  int m0 = blockIdx.x*64, n0 = blockIdx.y*64;
  int t = threadIdx.x, w = t >> 6, lr = t & 15, lk = (t & 63) >> 4;
  f32x4 acc[4] = {};
  int mrow = m0 + w*16 + lr;
  int sloc = mrow & 511;
  for (int kk = 0; kk < 5; ++kk) {
    int sh = sloc + kk - 2;
    bool ok = (sh >= 0) && (sh < 512);
    long arow = (long)mrow + kk - 2;
    for (int kb = 0; kb < 256; kb += 32) {
      short8 af = {};
      if (ok) af = *(const short8*)&xn[arow*256 + kb + lk*8];
#pragma unroll
      for (int g = 0; g < 4; ++g) {
        short8 bf = *(const short8*)&cw[(long)kk*65536 + (long)(n0 + g*16 + lr)*256 + kb + lk*8];
        acc[g] = __builtin_amdgcn_mfma_f32_16x16x32_bf16(af, bf, acc[g], 0, 0, 0);
      }
    }
  }
#pragma unroll
  for (int g = 0; g < 4; ++g) {
    int fo = n0 + g*16 + lr;
    float bv = cb[fo];
#pragma unroll
    for (int r = 0; r < 4; ++r) {
      long row = m0 + w*16 + lk*4 + r;
      float cv = acc[g][r] + bv;
      cv = fmaxf(cv, 0.1f*cv);
      long idx = row*256 + fo;
      io[idx] = f2bf(bf2f(io[idx]) + cv);
    }
  }
}

// ---------------- K/V projection (LDS-free GEMM, B from f32 weights inline) ----------------
__global__ __launch_bounds__(256) void kv_proj(
    const unsigned short* __restrict__ A, const float* __restrict__ wk,
    const float* __restrict__ wvv,
    unsigned short* __restrict__ kb, unsigned short* __restrict__ vb)
{
  int m0 = blockIdx.x*64, n0 = blockIdx.y*64;
  int t = threadIdx.x, w = t >> 6, lr = t & 15, lk = (t & 63) >> 4;
  f32x4 acc[4] = {};
  long arow = (long)(m0 + w*16 + lr);
  for (int k0 = 0; k0 < 256; k0 += 32) {
    short8 af = *(const short8*)&A[arow*256 + k0 + lk*8];
#pragma unroll
    for (int g = 0; g < 4; ++g) {
      int col = n0 + g*16 + lr;
      const float* ws = (col < 256) ? wk : wvv;
      short8 bf = cvt8(&ws[(long)(col & 255)*256 + k0 + lk*8]);
      acc[g] = __builtin_amdgcn_mfma_f32_16x16x32_bf16(af, bf, acc[g], 0, 0, 0);
    }
  }
#pragma unroll
  for (int g = 0; g < 4; ++g) {
    int col = n0 + g*16 + lr;
    int which = col >> 8, hh = (col >> 5) & 7, dd = col & 31;
    unsigned short* dst = (which == 0) ? kb : vb;
#pragma unroll
    for (int r = 0; r < 4; ++r) {
      int row = m0 + w*16 + lk*4 + r;
      int b = row >> 9, s = row & 511;
      dst[((long)(b*8 + hh)*512 + s)*32 + dd] = f2bf(acc[g][r]);
    }
  }
}

// ---------------- fused attention: Q-gen + QK^T + relbias + softmax + PV + leaky + LN + residual ----------------
__global__ __launch_bounds__(256) void attn(
    const unsigned short* __restrict__ kbuf, const unsigned short* __restrict__ vbuf,
    const unsigned short* __restrict__ x2, const float* __restrict__ wq,
    const float* __restrict__ rel, const float* __restrict__ lng, const float* __restrict__ lnb,
    float* __restrict__ outf, int b_base, int x2_boff)
{
  __shared__ __align__(16) unsigned short Qs[64*32];
  __shared__ __align__(16) unsigned short Ks[64*32];
  __shared__ __align__(16) unsigned short Vt[32*64];
  __shared__ __align__(16) unsigned short Ps[4][16*64];
  __shared__ float bl[128];
  int s0 = blockIdx.x*64, h = blockIdx.y, bg = b_base + blockIdx.z;
  int t = threadIdx.x;
  int w = t >> 6, l = t & 63, lr = l & 15, lk = l >> 4;
  int st = t >> 2, sc = (t & 3)*8;
  long bh = (long)(bg*8 + h);
  long x2r0 = (long)(bg - x2_boff)*512;

  // Q-gen: 64x32 tile from X2 rows, wq f32 inline-converted; scaled by 1/sqrt(D)
  {
    f32x4 qa[2] = {};
    long arow = x2r0 + s0 + w*16 + lr;
    for (int k0 = 0; k0 < 256; k0 += 32) {
      short8 af = *(const short8*)&x2[arow*256 + k0 + lk*8];
#pragma unroll
      for (int nt = 0; nt < 2; ++nt) {
        short8 bf = cvt8(&wq[((long)h*32 + nt*16 + lr)*256 + k0 + lk*8]);
        qa[nt] = __builtin_amdgcn_mfma_f32_16x16x32_bf16(af, bf, qa[nt], 0, 0, 0);
      }
    }
#pragma unroll
    for (int nt = 0; nt < 2; ++nt)
#pragma unroll
      for (int r = 0; r < 4; ++r)
        Qs[(w*16 + lk*4 + r)*32 + nt*16 + lr] = f2bf(qa[nt][r] * 0.17677669529663687f);
  }
  __syncthreads();
  short8 qf = *(const short8*)&Qs[(w*16 + lr)*32 + lk*8];

  f32x4 o[2] = {};
  float mrun[4] = {-3e38f, -3e38f, -3e38f, -3e38f};
  float lrun[4] = {0.f, 0.f, 0.f, 0.f};

  for (int t0 = 0; t0 < 512; t0 += 64) {
    __syncthreads();
    *(short8*)&Ks[st*32 + sc] = *(const short8*)&kbuf[(bh*512 + t0 + st)*32 + sc];
    short8 vv = *(const short8*)&vbuf[(bh*512 + t0 + st)*32 + sc];
#pragma unroll
    for (int jj = 0; jj < 8; ++jj) Vt[(sc + jj)*64 + st] = (unsigned short)vv[jj];
    if (t < 127) {
      int dd = s0 - t0 + t - 63;
      bl[t] = rel[(long)h*512 + (dd < 0 ? -dd : dd)];
    }
    __syncthreads();

    f32x4 zz = {};
    f32x4 sacc[4];
#pragma unroll
    for (int g = 0; g < 4; ++g) {
      short8 bf = *(const short8*)&Ks[(g*16 + lr)*32 + lk*8];
      sacc[g] = __builtin_amdgcn_mfma_f32_16x16x32_bf16(qf, bf, zz, 0, 0, 0);
    }
    float mx[4] = {-3e38f, -3e38f, -3e38f, -3e38f};
#pragma unroll
    for (int g = 0; g < 4; ++g)
#pragma unroll
      for (int r = 0; r < 4; ++r) {
        int iq = w*16 + lk*4 + r, jt = g*16 + lr;
        float val = sacc[g][r] + bl[iq - jt + 63];
        sacc[g][r] = val;
        mx[r] = fmaxf(mx[r], val);
      }
#pragma unroll
    for (int off = 1; off < 16; off <<= 1)
#pragma unroll
      for (int r = 0; r < 4; ++r) mx[r] = fmaxf(mx[r], __shfl_xor(mx[r], off));
    float scl[4];
#pragma unroll
    for (int r = 0; r < 4; ++r) {
      float mn = fmaxf(mrun[r], mx[r]);
      scl[r] = __expf(mrun[r] - mn);
      mrun[r] = mn;
    }
    float rs[4] = {0.f, 0.f, 0.f, 0.f};
#pragma unroll
    for (int g = 0; g < 4; ++g)
#pragma unroll
      for (int r = 0; r < 4; ++r) {
        float p = __expf(sacc[g][r] - mrun[r]);
        sacc[g][r] = p;
        rs[r] += p;
      }
#pragma unroll
    for (int off = 1; off < 16; off <<= 1)
#pragma unroll
      for (int r = 0; r < 4; ++r) rs[r] += __shfl_xor(rs[r], off);
#pragma unroll
    for (int r = 0; r < 4; ++r) {
      lrun[r] = lrun[r]*scl[r] + rs[r];
      o[0][r] *= scl[r];
      o[1][r] *= scl[r];
    }
#pragma unroll
    for (int g = 0; g < 4; ++g)
#pragma unroll
      for (int r = 0; r < 4; ++r)
        Ps[w][(lk*4 + r)*64 + g*16 + lr] = f2bf(sacc[g][r]);
    // Ps[w] is wave-private; same-wave DS write->read is in-order
#pragma unroll
    for (int ks = 0; ks < 2; ++ks) {
      short8 pa = *(const short8*)&Ps[w][lr*64 + ks*32 + lk*8];
#pragma unroll
      for (int g2 = 0; g2 < 2; ++g2) {
        short8 bv = *(const short8*)&Vt[(g2*16 + lr)*64 + ks*32 + lk*8];
        o[g2] = __builtin_amdgcn_mfma_f32_16x16x32_bf16(pa, bv, o[g2], 0, 0, 0);
      }
    }
  }

  float lg0 = lng[h*32 + lr], lg1 = lng[h*32 + 16 + lr];
  float lb0 = lnb[h*32 + lr], lb1 = lnb[h*32 + 16 + lr];
#pragma unroll
  for (int r = 0; r < 4; ++r) {
    float invl = 1.f / lrun[r];
    float a0 = o[0][r]*invl; a0 = fmaxf(a0, 0.1f*a0);
    float a1 = o[1][r]*invl; a1 = fmaxf(a1, 0.1f*a1);
    float s1 = a0 + a1, s2 = a0*a0 + a1*a1;
#pragma unroll
    for (int off = 1; off < 16; off <<= 1) {
      s1 += __shfl_xor(s1, off);
      s2 += __shfl_xor(s2, off);
    }
    float mu = s1*(1.f/32.f);
    float var = s2*(1.f/32.f) - mu*mu;
    float inv = rsqrtf(var + 1e-5f);
    int row = s0 + w*16 + lk*4 + r;
    long x2i = (x2r0 + row)*256 + h*32;
    long obase = ((long)(bg*512 + row))*256 + h*32;
    outf[obase + lr]      = bf2f(x2[x2i + lr])      + (a0 - mu)*inv*lg0 + lb0;
    outf[obase + 16 + lr] = bf2f(x2[x2i + 16 + lr]) + (a1 - mu)*inv*lg1 + lb1;
  }
}

// ---------------- host launch ----------------
extern "C" void kernel_launch(void* const* d_in, const int* in_sizes, int n_in,
                              void* d_out, int out_size, void* d_ws, size_t ws_size,
                              hipStream_t stream) {
  const float* x      = (const float*)d_in[0];
  const float* w_ih   = (const float*)d_in[1];
  const float* w_hh   = (const float*)d_in[2];
  const float* b_ih   = (const float*)d_in[3];
  const float* b_hh   = (const float*)d_in[4];
  const float* bn_g   = (const float*)d_in[5];
  const float* bn_b   = (const float*)d_in[6];
  const float* conv_w = (const float*)d_in[7];
  const float* conv_b = (const float*)d_in[8];
  const float* wq     = (const float*)d_in[9];
  const float* wk     = (const float*)d_in[10];
  const float* wvv    = (const float*)d_in[11];
  const float* rel    = (const float*)d_in[12];
  const float* ln_g   = (const float*)d_in[13];
  const float* ln_b   = (const float*)d_in[14];

  float* outf = (float*)d_out;
  unsigned short* dob = (unsigned short*)d_out;
  unsigned short* G0  = dob;              // [0,8M) bytes
  unsigned short* X1  = dob + 4194304;    // [8M,16M) bytes; becomes X2 in place
  unsigned short* XN  = dob;              // [0,8M) after G0 dead

  unsigned short* xs  = (unsigned short*)d_in[0];  // dead-input scratch (x)
  unsigned short* CW  = xs;                        // [0,655360) bytes in x
  unsigned short* KB  = xs;                        // [0,8M) in x
  unsigned short* VB  = xs + 4194304;              // [8M,16M) in x
  unsigned short* X2HI= xs;                        // [0,4M) in x (over dead K(b<16))
  float* STATS = (float*)d_in[4];                  // dead b_hh (6KB >= 2KB)

  // GRU layer 0 -> G0 bf16; layer 1 (+residual x) -> X1 bf16
  fused_gru<<<dim3(256, 2), 768, 0, stream>>>(x, nullptr, w_ih, w_hh, b_ih, b_hh, G0, 0);
  fused_gru<<<dim3(256, 2), 768, 0, stream>>>(x, G0,      w_ih, w_hh, b_ih, b_hh, X1, 1);

  // x and b_hh now dead -> scratch
  permute_cw<<<256, 256, 0, stream>>>(conv_w, CW);
  zero_stats<<<1, 512, 0, stream>>>(STATS);

  // BatchNorm
  bn_stats<<<256, 256, 0, stream>>>(X1, STATS);
  bn_apply<<<16384, 256, 0, stream>>>(X1, STATS, bn_g, bn_b, XN);

  // Conv + leaky + residual: X1 -> X2 (same-index RMW in d_out upper half)
  conv_gemm<<<dim3(256, 4), 256, 0, stream>>>(XN, CW, conv_b, X1);

  // K/V projection into dead x
  kv_proj<<<dim3(256, 8), 256, 0, stream>>>(X1, wk, wvv, KB, VB);

  // attention launch A: b<16, OUT f32 -> d_out[0,8M)
  attn<<<dim3(8, 8, 16), 256, 0, stream>>>(KB, VB, X1, wq, rel, ln_g, ln_b, outf, 0, 0);

  // move X2(b>=16) (4MB) out of d_out before launch B overwrites it
  hipMemcpyAsync(X2HI, (char*)d_out + 12582912, 4194304, hipMemcpyDeviceToDevice, stream);

  // attention launch B: b>=16, X2 from copy in x, OUT f32 -> d_out[8M,16M)
  attn<<<dim3(8, 8, 16), 256, 0, stream>>>(KB, VB, X2HI, wq, rel, ln_g, ln_b, outf, 16, 16);
}